// Round 5
// baseline (786.518 us; speedup 1.0000x reference)
//
#include <hip/hip_runtime.h>
#include <stdint.h>

#define N_PTS 8192
#define N_B 8
#define NGROUP 512
#define GSIZE 32
#define BIGF 1e10f

#define K1_THREADS 512
#define K1_PPT 16            // points per thread (8 packed pairs)
#define K1_WAVES 8

#define K2_THREADS 512
#define K2_PPT 16            // consecutive points per thread
#define K2_WAVES 8

typedef float f32x2 __attribute__((ext_vector_type(2)));

// ---------------- packed f32 ops (VOP3P) — bit-identical IEEE per half -----------------
__device__ __forceinline__ f32x2 pk_add(f32x2 a, f32x2 b) {
    f32x2 d; asm("v_pk_add_f32 %0, %1, %2" : "=v"(d) : "v"(a), "v"(b)); return d;
}
__device__ __forceinline__ f32x2 pk_sub(f32x2 a, f32x2 b) {   // a - b == a + (-b) exactly
    f32x2 d; asm("v_pk_add_f32 %0, %1, %2 neg_lo:[0,1] neg_hi:[0,1]" : "=v"(d) : "v"(a), "v"(b)); return d;
}
__device__ __forceinline__ f32x2 pk_mul(f32x2 a, f32x2 b) {
    f32x2 d; asm("v_pk_mul_f32 %0, %1, %2" : "=v"(d) : "v"(a), "v"(b)); return d;
}
__device__ __forceinline__ f32x2 pk_fma(f32x2 a, f32x2 b, f32x2 c) {  // a*b + c
    f32x2 d; asm("v_pk_fma_f32 %0, %1, %2, %3" : "=v"(d) : "v"(a), "v"(b), "v"(c)); return d;
}

// ---------------- DPP wave64 reductions (result valid in lane 63) ---------------------
#define DPP_RED_STEP_F(ctrl, rmask, op)                                            \
    v = op(v, __int_as_float(__builtin_amdgcn_update_dpp(                          \
            __float_as_int(v), __float_as_int(v), ctrl, rmask, 0xF, false)))

__device__ __forceinline__ float wave_fmax(float v) {
    DPP_RED_STEP_F(0x111, 0xF, fmaxf);
    DPP_RED_STEP_F(0x112, 0xF, fmaxf);
    DPP_RED_STEP_F(0x114, 0xF, fmaxf);
    DPP_RED_STEP_F(0x118, 0xF, fmaxf);
    DPP_RED_STEP_F(0x142, 0xA, fmaxf);
    DPP_RED_STEP_F(0x143, 0xC, fmaxf);
    return v;
}

#define DPP_RED_STEP_U(ctrl, rmask)                                                \
    { unsigned t = (unsigned)__builtin_amdgcn_update_dpp(                          \
            (int)v, (int)v, ctrl, rmask, 0xF, false);                              \
      v = (t < v) ? t : v; }

__device__ __forceinline__ unsigned wave_umin(unsigned v) {
    DPP_RED_STEP_U(0x111, 0xF);
    DPP_RED_STEP_U(0x112, 0xF);
    DPP_RED_STEP_U(0x114, 0xF);
    DPP_RED_STEP_U(0x118, 0xF);
    DPP_RED_STEP_U(0x142, 0xA);
    DPP_RED_STEP_U(0x143, 0xC);
    return v;
}

__device__ __forceinline__ int rdlane63_i(int v) {
    return __builtin_amdgcn_readlane(v, 63);
}

// u64 reduce across lanes 0..7 of each 16-lane row (inputs replicated at [lane&7]);
// result valid in lane 7.
#define U64_ROW8_STEP(ctrl, CMPOP)                                                 \
    { unsigned lo_ = (unsigned)v, hi_ = (unsigned)(v >> 32);                       \
      unsigned olo = (unsigned)__builtin_amdgcn_update_dpp((int)lo_, (int)lo_, ctrl, 0xF, 0xF, false); \
      unsigned ohi = (unsigned)__builtin_amdgcn_update_dpp((int)hi_, (int)hi_, ctrl, 0xF, 0xF, false); \
      unsigned long long o = ((unsigned long long)ohi << 32) | olo;                \
      if (o CMPOP v) v = o; }

__device__ __forceinline__ unsigned long long row8_u64_max(unsigned long long v) {
    U64_ROW8_STEP(0x111, >);
    U64_ROW8_STEP(0x112, >);
    U64_ROW8_STEP(0x114, >);
    return v;
}
__device__ __forceinline__ unsigned long long row8_u64_min(unsigned long long v) {
    U64_ROW8_STEP(0x111, <);
    U64_ROW8_STEP(0x112, <);
    U64_ROW8_STEP(0x114, <);
    return v;
}

// order-preserving float->uint transform
__device__ __forceinline__ unsigned fxform(unsigned u) {
    return u ^ (unsigned)(((int)u >> 31) | 0x80000000);
}

// ---------------- Kernel 1: farthest point sampling, one block per batch ---------------
extern "C" __global__ __launch_bounds__(K1_THREADS) void fps_kernel(
    const float* __restrict__ xyz, int* __restrict__ fps_idx)
{
    const int b   = blockIdx.x;
    const int tid = threadIdx.x;
    const float* base = xyz + (size_t)b * N_PTS * 6;

    __shared__ float lx[N_PTS], ly[N_PTS], lz[N_PTS];
    __shared__ unsigned long long pkey[2][K1_WAVES];

    // load 16 pts/thread (interleaved, coalesced) into packed pair regs + LDS staging
    float sx[K1_PPT], sy[K1_PPT], sz[K1_PPT];
#pragma unroll
    for (int i = 0; i < K1_PPT; ++i) {
        int p = tid + i * K1_THREADS;
        sx[i] = base[p * 6 + 0];
        sy[i] = base[p * 6 + 1];
        sz[i] = base[p * 6 + 2];
        lx[p] = sx[i]; ly[p] = sy[i]; lz[p] = sz[i];
    }
    f32x2 pX[8], pY[8], pZ[8];
    float dd[K1_PPT];
#pragma unroll
    for (int j = 0; j < 8; ++j) {
        pX[j] = (f32x2){sx[j], sx[j + 8]};
        pY[j] = (f32x2){sy[j], sy[j + 8]};
        pZ[j] = (f32x2){sz[j], sz[j + 8]};
        dd[j] = BIGF; dd[j + 8] = BIGF;
    }
    __syncthreads();

    const int lane = tid & 63;
    const int wid  = tid >> 6;
    int cur = 0;

    for (int it = 0; it < NGROUP; ++it) {
        if (tid == 0) fps_idx[b * NGROUP + it] = cur;
        if (it == NGROUP - 1) break;

        const int c = __builtin_amdgcn_readfirstlane(cur);
        const float cx = lx[c], cy = ly[c], cz = lz[c];
        const f32x2 cx2 = (f32x2){cx, cx};
        const f32x2 cy2 = (f32x2){cy, cy};
        const f32x2 cz2 = (f32x2){cz, cz};

        // packed min-update: d = (dx^2 + dy^2) + dz^2, exact order per half
#pragma unroll
        for (int j = 0; j < 8; ++j) {
            f32x2 dx = pk_sub(pX[j], cx2);
            f32x2 dy = pk_sub(pY[j], cy2);
            f32x2 dz = pk_sub(pZ[j], cz2);
            f32x2 s  = pk_add(pk_mul(dx, dx), pk_mul(dy, dy));
            f32x2 d  = pk_add(s, pk_mul(dz, dz));
            dd[j]     = fminf(dd[j],     d.x);
            dd[j + 8] = fminf(dd[j + 8], d.y);
        }

        // thread-local max
        float bestd = dd[0];
#pragma unroll
        for (int i = 1; i < K1_PPT; ++i) bestd = fmaxf(bestd, dd[i]);

        // wave max + post-scan for min global index among tied (slot-major order)
        float wm = __int_as_float(rdlane63_i(__float_as_int(wave_fmax(bestd))));
        int ii = K1_PPT;
#pragma unroll
        for (int i = K1_PPT - 1; i >= 0; --i) if (dd[i] == wm) ii = i;
        unsigned cand = (ii < K1_PPT) ? (unsigned)(tid + (ii << 9)) : 0xFFFFFFFFu;
        unsigned wi = (unsigned)rdlane63_i((int)wave_umin(cand));

        if (lane == 0)
            pkey[it & 1][wid] = ((unsigned long long)__float_as_uint(wm) << 32)
                              | (unsigned long long)(0xFFFFFFFFu - wi);
        __syncthreads();

        unsigned long long v = pkey[it & 1][lane & 7];
        v = row8_u64_max(v);
        unsigned klo = (unsigned)__builtin_amdgcn_readlane((int)(unsigned)v, 7);
        cur = (int)(0xFFFFFFFFu - klo);
    }
}

// ---------------- Kernel 2: 32-NN per (batch, group) + gather/write outputs -----------
extern "C" __global__ __launch_bounds__(K2_THREADS) void knn_kernel(
    const float* __restrict__ xyz, const int* __restrict__ fps_idx,
    float* __restrict__ out)
{
    const int bg  = blockIdx.x;
    const int b   = bg >> 9;
    const int g   = bg & (NGROUP - 1);
    const int tid = threadIdx.x;
    const float* base = xyz + (size_t)b * N_PTS * 6;

    const int q  = fps_idx[b * NGROUP + g];
    const int qq = __builtin_amdgcn_readfirstlane(q);
    const float cx = base[qq * 6 + 0];
    const float cy = base[qq * 6 + 1];
    const float cz = base[qq * 6 + 2];
    const float cn = __fadd_rn(__fadd_rn(__fmul_rn(cx, cx), __fmul_rn(cy, cy)),
                               __fmul_rn(cz, cz));
    const f32x2 cx2 = (f32x2){cx, cx};
    const f32x2 cy2 = (f32x2){cy, cy};
    const f32x2 cz2 = (f32x2){cz, cz};
    const f32x2 cn2 = (f32x2){cn, cn};
    const f32x2 two2 = (f32x2){2.0f, 2.0f};

    // 16 consecutive points per thread, loaded as 24 float4 (all bytes used, L1-resident)
    const float4* b4 = (const float4*)base;
    const int tb = tid * 24;

    unsigned long long keys[K2_PPT];
    unsigned long long lmin = ~0ull;

#pragma unroll
    for (int c = 0; c < 4; ++c) {
        float4 f0 = b4[tb + c * 6 + 0];
        float4 f1 = b4[tb + c * 6 + 1];
        float4 f2 = b4[tb + c * 6 + 2];
        float4 f3 = b4[tb + c * 6 + 3];
        float4 f4 = b4[tb + c * 6 + 4];
        float4 f5 = b4[tb + c * 6 + 5];
        // pts 4c+0:(f0.x,f0.y,f0.z) 4c+1:(f1.z,f1.w,f2.x) 4c+2:(f3.x,f3.y,f3.z) 4c+3:(f4.z,f4.w,f5.x)
        f32x2 Xa = (f32x2){f0.x, f3.x}, Ya = (f32x2){f0.y, f3.y}, Za = (f32x2){f0.z, f3.z};
        f32x2 Xb = (f32x2){f1.z, f4.z}, Yb = (f32x2){f1.w, f4.w}, Zb = (f32x2){f2.x, f5.x};

#pragma unroll
        for (int h = 0; h < 2; ++h) {
            f32x2 X = h ? Xb : Xa, Y = h ? Yb : Ya, Z = h ? Zb : Za;
            // ||x||^2 = (x^2+y^2)+z^2, no FMA
            f32x2 xn = pk_add(pk_add(pk_mul(X, X), pk_mul(Y, Y)), pk_mul(Z, Z));
            // dot: FMA chain ascending in k
            f32x2 dot = pk_mul(cx2, X);
            dot = pk_fma(cy2, Y, dot);
            dot = pk_fma(cz2, Z, dot);
            // d2 = (cn - 2*dot) + xn
            f32x2 d2 = pk_add(pk_sub(cn2, pk_mul(two2, dot)), xn);

            int p0 = tid * K2_PPT + c * 4 + h;        // lo half point
            int p1 = p0 + 2;                          // hi half point
            unsigned long long k0 =
                ((unsigned long long)fxform(__float_as_uint(d2.x)) << 32) | (unsigned)p0;
            unsigned long long k1 =
                ((unsigned long long)fxform(__float_as_uint(d2.y)) << 32) | (unsigned)p1;
            keys[c * 4 + h]     = k0;
            keys[c * 4 + h + 2] = k1;
            if (k0 < lmin) lmin = k0;
            if (k1 < lmin) lmin = k1;
        }
    }

    __shared__ unsigned long long part[2][K2_WAVES];
    __shared__ unsigned nlist[GSIZE];
    const int wid  = tid >> 6;
    const int lane = tid & 63;

    for (int r = 0; r < GSIZE; ++r) {
        // wave u64 min: two-phase (hi, then lo among hi-tied), branchless
        unsigned hi = (unsigned)(lmin >> 32);
        unsigned lo = (unsigned)(lmin & 0xFFFFFFFFull);
        unsigned wh = (unsigned)rdlane63_i((int)wave_umin(hi));
        unsigned cand = (hi == wh) ? lo : 0xFFFFFFFFu;
        unsigned wl = (unsigned)rdlane63_i((int)wave_umin(cand));

        if (lane == 0)
            part[r & 1][wid] = ((unsigned long long)wh << 32) | wl;
        __syncthreads();

        unsigned long long k = part[r & 1][lane & 7];
        k = row8_u64_min(k);
        {   // broadcast lane-7 result
            unsigned klo = (unsigned)__builtin_amdgcn_readlane((int)(unsigned)k, 7);
            unsigned khi = (unsigned)__builtin_amdgcn_readlane((int)(unsigned)(k >> 32), 7);
            k = ((unsigned long long)khi << 32) | klo;
        }
        if (tid == 0) nlist[r] = (unsigned)(k & 0xFFFFFFFFull);
        if (k == lmin) {   // exactly one thread wins (keys unique)
            lmin = ~0ull;
#pragma unroll
            for (int i = 0; i < K2_PPT; ++i) {
                if (keys[i] == k) keys[i] = ~0ull;
                if (keys[i] < lmin) lmin = keys[i];
            }
        }
    }
    __syncthreads();

    // ---- outputs ----
    const int OFF1 = N_B * NGROUP * GSIZE * 3;   // neigh_attr
    const int OFF2 = 2 * OFF1;                   // center
    const int OFF3 = OFF2 + N_B * NGROUP * 3;    // center_attribute

    if (tid < GSIZE) {
        unsigned p = nlist[tid];
        float x  = base[p * 6 + 0];
        float y  = base[p * 6 + 1];
        float z  = base[p * 6 + 2];
        float a0 = base[p * 6 + 3];
        float a1 = base[p * 6 + 4];
        float a2 = base[p * 6 + 5];
        size_t o = ((size_t)(b * NGROUP + g) * GSIZE + tid) * 3;
        out[o + 0] = __fsub_rn(x, cx);
        out[o + 1] = __fsub_rn(y, cy);
        out[o + 2] = __fsub_rn(z, cz);
        out[OFF1 + o + 0] = a0;
        out[OFF1 + o + 1] = a1;
        out[OFF1 + o + 2] = a2;
    } else if (tid == GSIZE) {
        size_t o = (size_t)(b * NGROUP + g) * 3;
        out[OFF2 + o + 0] = cx;
        out[OFF2 + o + 1] = cy;
        out[OFF2 + o + 2] = cz;
        out[OFF3 + o + 0] = base[qq * 6 + 3];
        out[OFF3 + o + 1] = base[qq * 6 + 4];
        out[OFF3 + o + 2] = base[qq * 6 + 5];
    }
}

extern "C" void kernel_launch(void* const* d_in, const int* in_sizes, int n_in,
                              void* d_out, int out_size, void* d_ws, size_t ws_size,
                              hipStream_t stream) {
    const float* xyz = (const float*)d_in[0];
    float* out = (float*)d_out;
    int* fps_idx = (int*)d_ws;   // 8*512 ints = 16 KB

    fps_kernel<<<N_B, K1_THREADS, 0, stream>>>(xyz, fps_idx);
    knn_kernel<<<N_B * NGROUP, K2_THREADS, 0, stream>>>(xyz, fps_idx, out);
}

// Round 6
// 706.731 us; speedup vs baseline: 1.1129x; 1.1129x over previous
//
#include <hip/hip_runtime.h>
#include <stdint.h>

#define N_PTS 8192
#define N_B 8
#define NGROUP 512
#define GSIZE 32
#define BIGF 1e10f

#define K1_THREADS 512
#define K1_PPT 16
#define K1_WAVES 8

#define K2_THREADS 512
#define K2_PPT 16
#define K2_WAVES 8

typedef float f32x2 __attribute__((ext_vector_type(2)));

// ---------------- packed f32 ops (VOP3P) — bit-identical IEEE per half ----------------
// (used only in knn key build — no throughput gain, but that path passed bit-exact)
__device__ __forceinline__ f32x2 pk_add(f32x2 a, f32x2 b) {
    f32x2 d; asm("v_pk_add_f32 %0, %1, %2" : "=v"(d) : "v"(a), "v"(b)); return d;
}
__device__ __forceinline__ f32x2 pk_sub(f32x2 a, f32x2 b) {
    f32x2 d; asm("v_pk_add_f32 %0, %1, %2 neg_lo:[0,1] neg_hi:[0,1]" : "=v"(d) : "v"(a), "v"(b)); return d;
}
__device__ __forceinline__ f32x2 pk_mul(f32x2 a, f32x2 b) {
    f32x2 d; asm("v_pk_mul_f32 %0, %1, %2" : "=v"(d) : "v"(a), "v"(b)); return d;
}
__device__ __forceinline__ f32x2 pk_fma(f32x2 a, f32x2 b, f32x2 c) {
    f32x2 d; asm("v_pk_fma_f32 %0, %1, %2, %3" : "=v"(d) : "v"(a), "v"(b), "v"(c)); return d;
}

// ---------------- DPP u64 reductions --------------------------------------------------
// gfx9 full-wave pattern: row_shr 1,2,4,8 + row_bcast15 (rmask 0xA) + row_bcast31 (0xC).
// bound_ctrl=false, old=src => masked/invalid lanes keep own value (identity).
#define U64_DPP_STEP(ctrl, rmask, CMPOP)                                           \
    { unsigned lo_ = (unsigned)v, hi_ = (unsigned)(v >> 32);                       \
      unsigned olo = (unsigned)__builtin_amdgcn_update_dpp((int)lo_, (int)lo_, ctrl, rmask, 0xF, false); \
      unsigned ohi = (unsigned)__builtin_amdgcn_update_dpp((int)hi_, (int)hi_, ctrl, rmask, 0xF, false); \
      unsigned long long o = ((unsigned long long)ohi << 32) | olo;                \
      if (o CMPOP v) v = o; }

__device__ __forceinline__ unsigned long long wave_u64_max(unsigned long long v) {
    U64_DPP_STEP(0x111, 0xF, >);
    U64_DPP_STEP(0x112, 0xF, >);
    U64_DPP_STEP(0x114, 0xF, >);
    U64_DPP_STEP(0x118, 0xF, >);
    U64_DPP_STEP(0x142, 0xA, >);
    U64_DPP_STEP(0x143, 0xC, >);
    return v;   // lane 63 valid
}
__device__ __forceinline__ unsigned long long wave_u64_min(unsigned long long v) {
    U64_DPP_STEP(0x111, 0xF, <);
    U64_DPP_STEP(0x112, 0xF, <);
    U64_DPP_STEP(0x114, 0xF, <);
    U64_DPP_STEP(0x118, 0xF, <);
    U64_DPP_STEP(0x142, 0xA, <);
    U64_DPP_STEP(0x143, 0xC, <);
    return v;   // lane 63 valid
}
// u64 max across lanes 0..7 of each 16-lane row (inputs replicated at [lane&7]); lane 7 valid
__device__ __forceinline__ unsigned long long row8_u64_max(unsigned long long v) {
    U64_DPP_STEP(0x111, 0xF, >);
    U64_DPP_STEP(0x112, 0xF, >);
    U64_DPP_STEP(0x114, 0xF, >);
    return v;
}

__device__ __forceinline__ unsigned long long rdlane_u64(unsigned long long v, int l) {
    unsigned lo = (unsigned)__builtin_amdgcn_readlane((int)(unsigned)v, l);
    unsigned hi = (unsigned)__builtin_amdgcn_readlane((int)(unsigned)(v >> 32), l);
    return ((unsigned long long)hi << 32) | lo;
}

// Exact (no-FMA) squared distance in numpy's evaluation order: (dx^2 + dy^2) + dz^2
__device__ __forceinline__ float sq_dist(float x, float y, float z,
                                         float cx, float cy, float cz) {
    float dx = __fsub_rn(x, cx);
    float dy = __fsub_rn(y, cy);
    float dz = __fsub_rn(z, cz);
    return __fadd_rn(__fadd_rn(__fmul_rn(dx, dx), __fmul_rn(dy, dy)), __fmul_rn(dz, dz));
}

__device__ __forceinline__ unsigned fxform(unsigned u) {
    return u ^ (unsigned)(((int)u >> 31) | 0x80000000);
}

// bitonic sort (ascending) of an N-element register array of u64
template<int N>
__device__ __forceinline__ void bitonic_sort(unsigned long long* a) {
#pragma unroll
    for (int k = 2; k <= N; k <<= 1) {
#pragma unroll
        for (int j = k >> 1; j > 0; j >>= 1) {
#pragma unroll
            for (int i = 0; i < N; ++i) {
                int ixj = i ^ j;
                if (ixj > i) {
                    bool up = ((i & k) == 0);
                    unsigned long long x = a[i], y = a[ixj];
                    bool sw = up ? (x > y) : (x < y);
                    if (sw) { a[i] = y; a[ixj] = x; }
                }
            }
        }
    }
}

// ---------------- Kernel 1: farthest point sampling, one block per batch ---------------
extern "C" __global__ __launch_bounds__(K1_THREADS) void fps_kernel(
    const float* __restrict__ xyz, int* __restrict__ fps_idx)
{
    const int b   = blockIdx.x;
    const int tid = threadIdx.x;
    const float* base = xyz + (size_t)b * N_PTS * 6;
    const float4* b4 = (const float4*)base;

    __shared__ float lx[N_PTS], ly[N_PTS], lz[N_PTS];
    __shared__ unsigned long long pkey[2][K1_WAVES];

    // 16 consecutive points per thread via 24 float4 loads (all bytes used)
    float sx[K1_PPT], sy[K1_PPT], sz[K1_PPT], dd[K1_PPT];
    const int tb = tid * 24;
#pragma unroll
    for (int c = 0; c < 4; ++c) {
        float4 f0 = b4[tb + c * 6 + 0];
        float4 f1 = b4[tb + c * 6 + 1];
        float4 f2 = b4[tb + c * 6 + 2];
        float4 f3 = b4[tb + c * 6 + 3];
        float4 f4 = b4[tb + c * 6 + 4];
        float4 f5 = b4[tb + c * 6 + 5];
        sx[c*4+0] = f0.x; sy[c*4+0] = f0.y; sz[c*4+0] = f0.z;
        sx[c*4+1] = f1.z; sy[c*4+1] = f1.w; sz[c*4+1] = f2.x;
        sx[c*4+2] = f3.x; sy[c*4+2] = f3.y; sz[c*4+2] = f3.z;
        sx[c*4+3] = f4.z; sy[c*4+3] = f4.w; sz[c*4+3] = f5.x;
    }
#pragma unroll
    for (int i = 0; i < K1_PPT; ++i) {
        int p = tid * K1_PPT + i;
        lx[p] = sx[i]; ly[p] = sy[i]; lz[p] = sz[i];
        dd[i] = BIGF;
    }
    __syncthreads();

    const int lane = tid & 63;
    const int wid  = tid >> 6;
    int cur = 0;

    for (int it = 0; it < NGROUP; ++it) {
        if (tid == 0) fps_idx[b * NGROUP + it] = cur;
        if (it == NGROUP - 1) break;

        const int c = __builtin_amdgcn_readfirstlane(cur);
        const float cx = lx[c], cy = ly[c], cz = lz[c];

        // min-update + inline first-max tracking (ascending i == ascending global p)
        float bestd = -1.0f;
        int   besti = 0;
#pragma unroll
        for (int i = 0; i < K1_PPT; ++i) {
            float d = sq_dist(sx[i], sy[i], sz[i], cx, cy, cz);
            dd[i] = fminf(dd[i], d);
            bool gt = dd[i] > bestd;
            bestd = gt ? dd[i] : bestd;
            besti = gt ? i : besti;
        }
        unsigned bestp = (unsigned)(tid * K1_PPT + besti);

        // single u64 wave max chain (dist bits hi, complemented idx lo => min-idx tiebreak)
        unsigned long long key =
            ((unsigned long long)__float_as_uint(bestd) << 32)
          | (unsigned long long)(0xFFFFFFFFu - bestp);
        key = wave_u64_max(key);
        if (lane == 63) pkey[it & 1][wid] = key;
        __syncthreads();

        unsigned long long v = pkey[it & 1][lane & 7];
        v = row8_u64_max(v);
        unsigned klo = (unsigned)__builtin_amdgcn_readlane((int)(unsigned)v, 7);
        cur = (int)(0xFFFFFFFFu - klo);
    }
}

// ---------------- Kernel 2: 32-NN per (batch, group) ----------------------------------
// Phase A: keys (exact d2 path, identical to R5-passing). Phase B: per-thread bitonic-16
// sort, per-wave barrier-free top-32 extraction into LDS. Phase C: single barrier; wave 0
// merges 8x32 candidates and writes all outputs; other waves exit.
extern "C" __global__ __launch_bounds__(K2_THREADS) void knn_kernel(
    const float* __restrict__ xyz, const int* __restrict__ fps_idx,
    float* __restrict__ out)
{
    const int bg  = blockIdx.x;
    const int b   = bg >> 9;
    const int g   = bg & (NGROUP - 1);
    const int tid = threadIdx.x;
    const float* base = xyz + (size_t)b * N_PTS * 6;

    const int q  = fps_idx[b * NGROUP + g];
    const int qq = __builtin_amdgcn_readfirstlane(q);
    const float cx = base[qq * 6 + 0];
    const float cy = base[qq * 6 + 1];
    const float cz = base[qq * 6 + 2];
    const float cn = __fadd_rn(__fadd_rn(__fmul_rn(cx, cx), __fmul_rn(cy, cy)),
                               __fmul_rn(cz, cz));
    const f32x2 cx2 = (f32x2){cx, cx};
    const f32x2 cy2 = (f32x2){cy, cy};
    const f32x2 cz2 = (f32x2){cz, cz};
    const f32x2 cn2 = (f32x2){cn, cn};
    const f32x2 two2 = (f32x2){2.0f, 2.0f};

    const float4* b4 = (const float4*)base;
    const int tb = tid * 24;

    unsigned long long keys[K2_PPT];

#pragma unroll
    for (int c = 0; c < 4; ++c) {
        float4 f0 = b4[tb + c * 6 + 0];
        float4 f1 = b4[tb + c * 6 + 1];
        float4 f2 = b4[tb + c * 6 + 2];
        float4 f3 = b4[tb + c * 6 + 3];
        float4 f4 = b4[tb + c * 6 + 4];
        float4 f5 = b4[tb + c * 6 + 5];
        f32x2 Xa = (f32x2){f0.x, f3.x}, Ya = (f32x2){f0.y, f3.y}, Za = (f32x2){f0.z, f3.z};
        f32x2 Xb = (f32x2){f1.z, f4.z}, Yb = (f32x2){f1.w, f4.w}, Zb = (f32x2){f2.x, f5.x};

#pragma unroll
        for (int h = 0; h < 2; ++h) {
            f32x2 X = h ? Xb : Xa, Y = h ? Yb : Ya, Z = h ? Zb : Za;
            f32x2 xn = pk_add(pk_add(pk_mul(X, X), pk_mul(Y, Y)), pk_mul(Z, Z));
            f32x2 dot = pk_mul(cx2, X);
            dot = pk_fma(cy2, Y, dot);
            dot = pk_fma(cz2, Z, dot);
            f32x2 d2 = pk_add(pk_sub(cn2, pk_mul(two2, dot)), xn);

            int p0 = tid * K2_PPT + c * 4 + h;
            int p1 = p0 + 2;
            keys[c * 4 + h] =
                ((unsigned long long)fxform(__float_as_uint(d2.x)) << 32) | (unsigned)p0;
            keys[c * 4 + h + 2] =
                ((unsigned long long)fxform(__float_as_uint(d2.y)) << 32) | (unsigned)p1;
        }
    }

    // per-thread ascending sort; candidate is keys[0]
    bitonic_sort<K2_PPT>(keys);

    __shared__ unsigned long long wtop[K2_WAVES][GSIZE];
    const int wid  = tid >> 6;
    const int lane = tid & 63;

    // per-wave top-32 extraction, no barriers
    for (int r = 0; r < GSIZE; ++r) {
        unsigned long long wk = wave_u64_min(keys[0]);
        unsigned long long wkey = rdlane_u64(wk, 63);
        if (lane == 0) wtop[wid][r] = wkey;
        if (keys[0] == wkey) {   // exactly one lane wins
#pragma unroll
            for (int i = 0; i < K2_PPT - 1; ++i) keys[i] = keys[i + 1];
            keys[K2_PPT - 1] = ~0ull;
        }
    }
    __syncthreads();
    if (wid != 0) return;   // no barriers after this point

    // wave 0 merges 256 candidates: 4 per lane, sorted, 32 extraction rounds
    unsigned long long mk[4];
#pragma unroll
    for (int j = 0; j < 4; ++j) {
        int f = lane + 64 * j;
        mk[j] = wtop[f >> 5][f & 31];
    }
    bitonic_sort<4>(mk);

    unsigned myp = 0;
    for (int r = 0; r < GSIZE; ++r) {
        unsigned long long wk = wave_u64_min(mk[0]);
        unsigned long long wkey = rdlane_u64(wk, 63);
        if (lane == r) myp = (unsigned)(wkey & 0xFFFFFFFFull);
        if (mk[0] == wkey) {
            mk[0] = mk[1]; mk[1] = mk[2]; mk[2] = mk[3]; mk[3] = ~0ull;
        }
    }

    // ---- outputs (wave 0 only) ----
    const int OFF1 = N_B * NGROUP * GSIZE * 3;   // neigh_attr
    const int OFF2 = 2 * OFF1;                   // center
    const int OFF3 = OFF2 + N_B * NGROUP * 3;    // center_attribute

    if (lane < GSIZE) {
        unsigned p = myp;
        float x  = base[p * 6 + 0];
        float y  = base[p * 6 + 1];
        float z  = base[p * 6 + 2];
        float a0 = base[p * 6 + 3];
        float a1 = base[p * 6 + 4];
        float a2 = base[p * 6 + 5];
        size_t o = ((size_t)(b * NGROUP + g) * GSIZE + lane) * 3;
        out[o + 0] = __fsub_rn(x, cx);
        out[o + 1] = __fsub_rn(y, cy);
        out[o + 2] = __fsub_rn(z, cz);
        out[OFF1 + o + 0] = a0;
        out[OFF1 + o + 1] = a1;
        out[OFF1 + o + 2] = a2;
    } else if (lane == GSIZE) {
        size_t o = (size_t)(b * NGROUP + g) * 3;
        out[OFF2 + o + 0] = cx;
        out[OFF2 + o + 1] = cy;
        out[OFF2 + o + 2] = cz;
        out[OFF3 + o + 0] = base[qq * 6 + 3];
        out[OFF3 + o + 1] = base[qq * 6 + 4];
        out[OFF3 + o + 2] = base[qq * 6 + 5];
    }
}

extern "C" void kernel_launch(void* const* d_in, const int* in_sizes, int n_in,
                              void* d_out, int out_size, void* d_ws, size_t ws_size,
                              hipStream_t stream) {
    const float* xyz = (const float*)d_in[0];
    float* out = (float*)d_out;
    int* fps_idx = (int*)d_ws;   // 8*512 ints = 16 KB

    fps_kernel<<<N_B, K1_THREADS, 0, stream>>>(xyz, fps_idx);
    knn_kernel<<<N_B * NGROUP, K2_THREADS, 0, stream>>>(xyz, fps_idx, out);
}